// Round 11
// baseline (844.491 us; speedup 1.0000x reference)
//
#include <hip/hip_runtime.h>
#include <hip/hip_fp16.h>

typedef _Float16 f16;
typedef _Float16 f16x4 __attribute__((ext_vector_type(4)));
typedef _Float16 f16x8 __attribute__((ext_vector_type(8)));
typedef float    f32x4 __attribute__((ext_vector_type(4)));

#define NEG_INF (-__builtin_inff())
#define AS1 __attribute__((address_space(1)))
#define AS3 __attribute__((address_space(3)))
#define GLOAD_LDS16(g, l) \
    __builtin_amdgcn_global_load_lds((AS1 const void*)(g), (AS3 void*)(l), 16, 0, 0)
// v_exp_f32 computes 2^x; this builtin maps to it directly (NOT __exp2f, which
// collides with glibc math.h and does not exist as a HIP device function).
#define EXP2F(x) __builtin_amdgcn_exp2f(x)
// scale * log2(e): softmax runs in the log2 domain; folded into Q at GEMM epilogue.
#define QSCL2 (0.08838834764831845f * 1.4426950408889634f)
// s_barrier is IntrNoMem at IR level: bracket with compile-time fences so no
// memory op (ds_read / global_load_lds) can be scheduled across a phase edge.
#define BARRIER() do { asm volatile("" ::: "memory"); \
                       __builtin_amdgcn_s_barrier(); \
                       asm volatile("" ::: "memory"); } while (0)

// ---------------------------------------------------------------- converts
__global__ __launch_bounds__(256) void cvt_f32_f16(const float* __restrict__ in,
                                                   f16* __restrict__ out, int n4) {
    int i = blockIdx.x * 256 + threadIdx.x;
    if (i >= n4) return;
    float4 v = ((const float4*)in)[i];
    f16x4 h = {(f16)v.x, (f16)v.y, (f16)v.z, (f16)v.w};
    ((f16x4*)out)[i] = h;
}

// ---------------------------------------------------------------- GEMM C = A * Bt^T
// K-loop FROZEN (r8, 258-260 us, MfmaUtil ~34): r3 barrier/staging ledger +
// fragment prefetch under MFMA clusters. r4/r6/r8 scheduling attempts were
// null/negative; cross-wave overlap already hides LDS reads. Do not touch.
//
// r11: ROPE template flag fuses RoPE + paged-cache scatter into the EPILOGUE
// (K-loop untouched). Partner element (col^1) lives in lane^1 (m16 parity):
// one shfl_xor pairs (x0,x1). Section (q/k/v) is block-uniform (bn multiple
// of 256; boundaries 4096/5120 are 256-aligned). Q is pre-scaled by
// scale*log2e here (attn consumes it directly). RoPE now applies to the
// pre-f16-rounding f32 accumulator (slightly MORE accurate than the old
// separate rope_qk pass over f16 data).
template <typename CT, bool ROPE>
__global__ __launch_bounds__(512) void gemm256(const f16* __restrict__ A,
                                               const f16* __restrict__ Bt,
                                               CT* __restrict__ C,
                                               int M, int N, int K,
                                               const float* __restrict__ freqs,
                                               f16* __restrict__ qrope,
                                               f16* __restrict__ krope) {
    __shared__ __align__(16) f16 smem[65536];     // LA[2][2][8192] | LB[2][2][8192]
    f16* LA = smem;
    f16* LB = smem + 32768;

    const int tid  = threadIdx.x;
    const int wave = tid >> 6, lane = tid & 63;
    const int quad = lane >> 4, m16 = lane & 15;
    const int wm = wave >> 2, wn = wave & 3;

    // bijective XCD-aware block swizzle (m204 form)
    const int ntn = N >> 8;
    const int nwg = (M >> 8) * ntn;
    const int q8 = nwg >> 3, r8 = nwg & 7;
    const int xcd = blockIdx.x & 7, idx = blockIdx.x >> 3;
    const int swz = (xcd < r8 ? xcd * (q8 + 1) : r8 * (q8 + 1) + (xcd - r8) * q8) + idx;
    const int bm = (swz / ntn) << 8;
    const int bn = (swz % ntn) << 8;

    // staging: thread tid fills linear LDS elems tid*8 (+4096 for rows 64..127);
    // source column-granule XOR-pre-permuted so swizzled reads see logical data.
    const int rowW = tid >> 3;                         // 0..63
    const int gsrc = (tid & 7) ^ (rowW & 7);
    const f16* gA0 = A  + (size_t)(bm + rowW) * K + gsrc * 8;
    const f16* gA1 = A  + (size_t)(bm + 128 + rowW) * K + gsrc * 8;
    const f16* gB0 = Bt + (size_t)(bn + rowW) * K + gsrc * 8;
    const f16* gB1 = Bt + (size_t)(bn + 128 + rowW) * K + gsrc * 8;
    const size_t rstep = (size_t)64 * K;
    const int lw = wave * 512;                         // wave-uniform LDS elem offset

#define STG(dstbase, gp, kt) do { \
    GLOAD_LDS16((gp) + (size_t)(kt) * 64,         (dstbase) + lw); \
    GLOAD_LDS16((gp) + (size_t)(kt) * 64 + rstep, (dstbase) + lw + 4096); } while (0)

    // fragment LDS offsets (elems): row*64 + (((ks*4+quad) ^ (row&7))*8
    int foff[2];
#pragma unroll
    for (int ks = 0; ks < 2; ++ks)
        foff[ks] = (((ks << 2) | quad) ^ (m16 & 7)) * 8;
    const int arow = wm * 8192 + m16 * 64;             // + mt*1024
    const int brow = (wn >> 1) * 8192 + (wn & 1) * 4096 + m16 * 64;   // + nt*1024

    f32x4 acc[8][4];
#pragma unroll
    for (int i = 0; i < 8; ++i)
#pragma unroll
        for (int j = 0; j < 4; ++j)
#pragma unroll
            for (int e = 0; e < 4; ++e) acc[i][j][e] = 0.f;

    const int NT = K >> 6;

    // prologue: tile0 {A0,A1,B0,B1} + tile1 {B0,B1}; vmcnt(4) lands tile0;
    // then prefetch tile0's ph0 fragments (afA m0 + bf0) before entering loop.
    STG(LA, gA0, 0); STG(LA + 8192, gA1, 0);
    STG(LB, gB0, 0); STG(LB + 8192, gB1, 0);
    STG(LB + 16384, gB0, 1); STG(LB + 16384 + 8192, gB1, 1);
    asm volatile("s_waitcnt vmcnt(4)" ::: "memory");
    BARRIER();

    f16x8 afA[4][2], afB[4][2], bf0[2][2], bf1[2][2];
#pragma unroll
    for (int mt = 0; mt < 4; ++mt)
#pragma unroll
        for (int ks = 0; ks < 2; ++ks)
            afA[mt][ks] = *(const f16x8*)(LA + arow + mt * 1024 + foff[ks]);
#pragma unroll
    for (int nt = 0; nt < 2; ++nt)
#pragma unroll
        for (int ks = 0; ks < 2; ++ks)
            bf0[nt][ks] = *(const f16x8*)(LB + brow + nt * 1024 + foff[ks]);

    for (int t = 0; t < NT; ++t) {
        const int bo = (t & 1) * 16384;
        const f16* pa = LA + bo + arow;
        const f16* pb = LB + bo + brow;
        const f16* pa1 = LA + (bo ^ 16384) + arow;     // next tile's buffer
        const f16* pb1 = LB + (bo ^ 16384) + brow;

        // ---- phase 0: stage A-h0(t+1); MFMA(afA,bf0) ∥ prefetch bf1(t)
        if (t + 1 < NT) STG(LA + (bo ^ 16384), gA0, t + 1);
        BARRIER();
        asm volatile("s_waitcnt lgkmcnt(0)" ::: "memory");
        __builtin_amdgcn_s_setprio(1);
#pragma unroll
        for (int nt = 0; nt < 2; ++nt)
#pragma unroll
            for (int ks = 0; ks < 2; ++ks)
                bf1[nt][ks] = *(const f16x8*)(pb + (nt + 2) * 1024 + foff[ks]);
#pragma unroll
        for (int mt = 0; mt < 4; ++mt)
#pragma unroll
            for (int nt = 0; nt < 2; ++nt)
#pragma unroll
                for (int ks = 0; ks < 2; ++ks)
                    acc[mt][nt] = __builtin_amdgcn_mfma_f32_16x16x32_f16(
                        afA[mt][ks], bf0[nt][ks], acc[mt][nt], 0, 0, 0);
        __builtin_amdgcn_s_setprio(0);
        BARRIER();

        // ---- phase 1: stage A-h1(t+1); MFMA(afA,bf1) ∥ prefetch afB(t,m1)
        if (t + 1 < NT) STG(LA + (bo ^ 16384) + 8192, gA1, t + 1);
        BARRIER();
        asm volatile("s_waitcnt lgkmcnt(0)" ::: "memory");
        __builtin_amdgcn_s_setprio(1);
#pragma unroll
        for (int mt = 0; mt < 4; ++mt)
#pragma unroll
            for (int ks = 0; ks < 2; ++ks)
                afB[mt][ks] = *(const f16x8*)(pa + (mt + 4) * 1024 + foff[ks]);
#pragma unroll
        for (int mt = 0; mt < 4; ++mt)
#pragma unroll
            for (int nt = 0; nt < 2; ++nt)
#pragma unroll
                for (int ks = 0; ks < 2; ++ks)
                    acc[mt][nt + 2] = __builtin_amdgcn_mfma_f32_16x16x32_f16(
                        afA[mt][ks], bf1[nt][ks], acc[mt][nt + 2], 0, 0, 0);
        __builtin_amdgcn_s_setprio(0);
        BARRIER();

        // ---- phase 2: stage B-h0(t+2); MFMA(afB,bf1)
        if (t + 2 < NT) STG(LB + bo, gB0, t + 2);
        BARRIER();
        asm volatile("s_waitcnt lgkmcnt(0)" ::: "memory");
        __builtin_amdgcn_s_setprio(1);
#pragma unroll
        for (int mt = 0; mt < 4; ++mt)
#pragma unroll
            for (int nt = 0; nt < 2; ++nt)
#pragma unroll
                for (int ks = 0; ks < 2; ++ks)
                    acc[mt + 4][nt + 2] = __builtin_amdgcn_mfma_f32_16x16x32_f16(
                        afB[mt][ks], bf1[nt][ks], acc[mt + 4][nt + 2], 0, 0, 0);
        __builtin_amdgcn_s_setprio(0);
        BARRIER();

        // ---- phase 3: stage B-h1(t+2); vmcnt+BAR (A/B(t+1) visible);
        //      MFMA(afB,bf0) ∥ prefetch afA(t+1); THEN prefetch bf0(t+1)
        //      (bf0(t) must be consumed by the MFMA before being overwritten)
        if (t + 2 < NT) STG(LB + bo + 8192, gB1, t + 2);
        if (t + 2 < NT) { asm volatile("s_waitcnt vmcnt(4)" ::: "memory"); }
        else            { asm volatile("s_waitcnt vmcnt(0)" ::: "memory"); }
        BARRIER();
        __builtin_amdgcn_s_setprio(1);
        if (t + 1 < NT) {
#pragma unroll
            for (int mt = 0; mt < 4; ++mt)
#pragma unroll
                for (int ks = 0; ks < 2; ++ks)
                    afA[mt][ks] = *(const f16x8*)(pa1 + mt * 1024 + foff[ks]);
        }
#pragma unroll
        for (int mt = 0; mt < 4; ++mt)
#pragma unroll
            for (int nt = 0; nt < 2; ++nt)
#pragma unroll
                for (int ks = 0; ks < 2; ++ks)
                    acc[mt + 4][nt] = __builtin_amdgcn_mfma_f32_16x16x32_f16(
                        afB[mt][ks], bf0[nt][ks], acc[mt + 4][nt], 0, 0, 0);
        if (t + 1 < NT) {
#pragma unroll
            for (int nt = 0; nt < 2; ++nt)
#pragma unroll
                for (int ks = 0; ks < 2; ++ks)
                    bf0[nt][ks] = *(const f16x8*)(pb1 + nt * 1024 + foff[ks]);
        }
        __builtin_amdgcn_s_setprio(0);
        BARRIER();
    }
#undef STG

    // epilogue: row = bm + wm*128 + mt*16 + quad*4 + r, col = bn + wn*64 + nt*16 + m16
    if (ROPE && bn < 5120) {
        // q section (bn<4096) or k section (4096<=bn<5120): RoPE + scatter.
        // qkv row layout: q 0:4096 | k 4096:5120 (head = col>>7).
        const bool isq = bn < 4096;
#pragma unroll
        for (int mt = 0; mt < 8; ++mt)
#pragma unroll
            for (int r = 0; r < 4; ++r) {
                int row = bm + wm * 128 + mt * 16 + quad * 4 + r;
                int b = row >> 11, s = row & 2047;
                const float* fr = freqs + (size_t)s * 128;
#pragma unroll
                for (int nt = 0; nt < 4; ++nt) {
                    int col = bn + wn * 64 + nt * 16 + m16;
                    float v  = acc[mt][nt][r];
                    float vp = __shfl_xor(v, 1, 64);       // partner col^1 (lane^1)
                    float cs = fr[col & 126];
                    float sn = fr[(col & 126) + 1];
                    // even d: x0*cos - x1*sin ; odd d: x1*cos + x0*sin
                    float o = (m16 & 1) ? (v * cs + vp * sn) : (v * cs - vp * sn);
                    f16* dst;
                    if (isq) {
                        o *= QSCL2;                        // fold softmax scale into Q
                        dst = qrope + (((size_t)(b * 32 + (col >> 7))) * 2048 + s) * 128 + (col & 127);
                    } else {
                        dst = krope + (((size_t)(b * 8 + ((col >> 7) - 32))) * 2048 + s) * 128 + (col & 127);
                    }
                    *dst = (f16)o;
                }
            }
    } else {
#pragma unroll
        for (int mt = 0; mt < 8; ++mt)
#pragma unroll
            for (int r = 0; r < 4; ++r) {
                int row = bm + wm * 128 + mt * 16 + quad * 4 + r;
                CT* cp = C + (size_t)row * N + bn + wn * 64 + m16;
#pragma unroll
                for (int nt = 0; nt < 4; ++nt) cp[nt * 16] = (CT)acc[mt][nt][r];
            }
    }
}

// ---------------------------------------------------------------- V transpose (LDS-tiled)
__global__ __launch_bounds__(256) void transpose_v(const f16* __restrict__ qkv,
                                                   f16* __restrict__ vvt) {
    __shared__ f16 T[64][72];
    const int st = blockIdx.x, dt = blockIdx.y;
    const int b = blockIdx.z >> 3, kvh = blockIdx.z & 7;
    const int tid = threadIdx.x;
    const int sr = tid >> 3, c8 = (tid & 7) * 8;
#pragma unroll
    for (int rep = 0; rep < 2; ++rep) {
        int sl = rep * 32 + sr;
        *(f16x8*)&T[sl][c8] =
            *(const f16x8*)(qkv + (size_t)(b * 2048 + st * 64 + sl) * 6144
                            + 5120 + kvh * 128 + dt * 64 + c8);
    }
    __syncthreads();
#pragma unroll
    for (int rep = 0; rep < 2; ++rep) {
        int dl = rep * 32 + sr;
        f16x8 v;
#pragma unroll
        for (int j = 0; j < 8; ++j) v[j] = T[c8 + j][dl];
        *(f16x8*)(vvt + (((size_t)(b * 8 + kvh)) * 128 + dt * 64 + dl) * 2048
                  + st * 64 + c8) = v;
    }
}

// ---------------------------------------------------------------- flash attention v7b
// v7 structure (512 thr / 8 waves, QBLK=128, 2 barriers/ktile, T14 async
// staging, mask-skip, defer-rescale, partial l_i). Q arrives PRE-SCALED by
// scale*log2e from the fused GEMM epilogue (no per-half scaling loop here).
__global__ __launch_bounds__(512) void attn_fused(const f16* __restrict__ qh,
                                                  const f16* __restrict__ kk,
                                                  const f16* __restrict__ vvt,
                                                  const int* __restrict__ seqlens,
                                                  f16* __restrict__ out) {
    __shared__ f16 Ks[64 * 136];     // [key][d] stride 136
    __shared__ f16 Vs[128][72];      // [d][key] stride 72 (2-way free)
    __shared__ f16 Ps[128 * 72];     // [qrow][key] stride 72, wave-private rows
    const int pair = blockIdx.x;     // 0..7
    const int h = blockIdx.y, b = blockIdx.z;
    const int kvh = h >> 2;
    const int tid = threadIdx.x, wave = tid >> 6, lane = tid & 63;
    const int quad = lane >> 4, m16 = lane & 15;

    const int seqlen = seqlens[b];
    const f16* kbp = kk  + ((size_t)(b * 8 + kvh) * 2048) * 128;
    const f16* vbp = vvt + ((size_t)(b * 8 + kvh) * 128) * 2048;

    for (int half = 0; half < 2; ++half) {
        const int qt = half ? pair : (15 - pair);   // heavy tile first
        const int qbase = qt * 128;
        const int qw = qbase + wave * 16;

        const f16* qptr = qh + (((size_t)(b * 32 + h)) * 2048 + qw + m16) * 128;
        f16x8 qf[4];
#pragma unroll
        for (int c = 0; c < 4; ++c) qf[c] = *(const f16x8*)(qptr + c * 32 + quad * 8);

        float m_i[4], l_i[4];
        f32x4 oacc[8];
#pragma unroll
        for (int r = 0; r < 4; ++r) { m_i[r] = NEG_INF; l_i[r] = 0.f; }
#pragma unroll
        for (int dt = 0; dt < 8; ++dt)
#pragma unroll
            for (int e = 0; e < 4; ++e) oacc[dt][e] = 0.f;

        int kmax = qbase + 128; if (seqlen < kmax) kmax = seqlen;

        // prefetch tile 0 into registers (512 threads: 2 chunks each of K and V)
        f16x8 gk[2], gv[2];
#pragma unroll
        for (int it = 0; it < 2; ++it) {
            int g = it * 512 + tid;
            gk[it] = *(const f16x8*)(kbp + (size_t)(g >> 4) * 128 + (g & 15) * 8);
            gv[it] = *(const f16x8*)(vbp + (size_t)(g >> 3) * 2048 + (g & 7) * 8);
        }

        for (int kt = 0; kt < kmax; kt += 64) {
            BARRIER();   // all waves' Ks/Vs reads of prev iter are complete
            // reg -> LDS (K tile: 64 keys x 128 d; V^T tile: 128 d x 64 keys)
#pragma unroll
            for (int it = 0; it < 2; ++it) {
                int g = it * 512 + tid;
                *(f16x8*)&Ks[(g >> 4) * 136 + (g & 15) * 8] = gk[it];
                *(f16x8*)&Vs[g >> 3][(g & 7) * 8] = gv[it];
            }
            // issue next tile's loads; they stay in flight across the barrier
            if (kt + 64 < kmax) {
#pragma unroll
                for (int it = 0; it < 2; ++it) {
                    int g = it * 512 + tid;
                    gk[it] = *(const f16x8*)(kbp + (size_t)(kt + 64 + (g >> 4)) * 128 + (g & 15) * 8);
                    gv[it] = *(const f16x8*)(vbp + (size_t)(g >> 3) * 2048 + (kt + 64) + (g & 7) * 8);
                }
            }
            asm volatile("s_waitcnt lgkmcnt(0)" ::: "memory");  // LDS writes visible
            BARRIER();                                          // vmcnt NOT drained

            // S = Q K^T (Q pre-scaled, log2 domain)
            f32x4 sc[4];
#pragma unroll
            for (int nt = 0; nt < 4; ++nt) {
                f32x4 s = {0.f, 0.f, 0.f, 0.f};
#pragma unroll
                for (int c = 0; c < 4; ++c) {
                    f16x8 kf = *(const f16x8*)&Ks[(nt * 16 + m16) * 136 + c * 32 + quad * 8];
                    s = __builtin_amdgcn_mfma_f32_16x16x32_f16(qf[c], kf, s, 0, 0, 0);
                }
                sc[nt] = s;
            }

            // mask only on diagonal/partial tiles (wave-uniform branch)
            float sv[4][4];
            float mt[4] = {NEG_INF, NEG_INF, NEG_INF, NEG_INF};
            if (kt + 63 <= qw && kt + 64 <= seqlen) {
#pragma unroll
                for (int nt = 0; nt < 4; ++nt)
#pragma unroll
                    for (int r = 0; r < 4; ++r) {
                        float sx = sc[nt][r];
                        sv[nt][r] = sx;
                        mt[r] = fmaxf(mt[r], sx);
                    }
            } else {
#pragma unroll
                for (int nt = 0; nt < 4; ++nt) {
                    int kpos = kt + nt * 16 + m16;
#pragma unroll
                    for (int r = 0; r < 4; ++r) {
                        int qpos = qw + quad * 4 + r;
                        float sx = sc[nt][r];
                        sx = (kpos <= qpos && kpos < seqlen) ? sx : NEG_INF;
                        sv[nt][r] = sx;
                        mt[r] = fmaxf(mt[r], sx);
                    }
                }
            }
#pragma unroll
            for (int off = 1; off < 16; off <<= 1)
#pragma unroll
                for (int r = 0; r < 4; ++r)
                    mt[r] = fmaxf(mt[r], __shfl_xor(mt[r], off, 64));

            // exact defer: skip alpha+rescale entirely when no row's max grew
            // (alpha==1). mt/m_i uniform across m16; branch diverges only
            // across quad groups (both paths per-lane correct).
            float mm[4];
            bool grow = (mt[0] > m_i[0]) | (mt[1] > m_i[1]) |
                        (mt[2] > m_i[2]) | (mt[3] > m_i[3]);
            if (grow) {
#pragma unroll
                for (int r = 0; r < 4; ++r) {
                    float mo = m_i[r];
                    float mn = fmaxf(mo, mt[r]);
                    float mmr = fmaxf(mn, -1e30f);
                    float a = EXP2F(mo - mmr);
                    m_i[r] = mn;
                    mm[r] = mmr;
                    l_i[r] *= a;     // per-lane PARTIAL; a uniform across m16
#pragma unroll
                    for (int dt = 0; dt < 8; ++dt) oacc[dt][r] *= a;
                }
            } else {
#pragma unroll
                for (int r = 0; r < 4; ++r) mm[r] = fmaxf(m_i[r], -1e30f);
            }
            // per-lane partial row-sum: no cross-lane reduce here (epilogue)
#pragma unroll
            for (int nt = 0; nt < 4; ++nt)
#pragma unroll
                for (int r = 0; r < 4; ++r) {
                    float pv = EXP2F(sv[nt][r] - mm[r]);
                    sv[nt][r] = pv;
                    l_i[r] += pv;
                }

            // P: C-layout regs -> WAVE-PRIVATE Ps rows -> A-layout fragments.
            // No barrier: rows [wave*16, wave*16+16) are touched only by this
            // wave; compiler orders the ds_write -> ds_read via lgkmcnt.
#pragma unroll
            for (int nt = 0; nt < 4; ++nt)
#pragma unroll
                for (int r = 0; r < 4; ++r)
                    Ps[(wave * 16 + quad * 4 + r) * 72 + nt * 16 + m16] = (f16)sv[nt][r];

            f16x8 pf[2];
#pragma unroll
            for (int c = 0; c < 2; ++c)
                pf[c] = *(const f16x8*)&Ps[(wave * 16 + m16) * 72 + c * 32 + quad * 8];
#pragma unroll
            for (int dt = 0; dt < 8; ++dt)
#pragma unroll
                for (int c = 0; c < 2; ++c) {
                    f16x8 vf = *(const f16x8*)&Vs[dt * 16 + m16][c * 32 + quad * 8];
                    oacc[dt] = __builtin_amdgcn_mfma_f32_16x16x32_f16(pf[c], vf, oacc[dt], 0, 0, 0);
                }
        }

        // epilogue: ONE cross-lane reduce of the partial l_i, then normalize
#pragma unroll
        for (int off = 1; off < 16; off <<= 1)
#pragma unroll
            for (int r = 0; r < 4; ++r) l_i[r] += __shfl_xor(l_i[r], off, 64);
#pragma unroll
        for (int r = 0; r < 4; ++r) {
            int qpos = qw + quad * 4 + r;
            float inv = 1.0f / l_i[r];
            f16* op = out + ((size_t)b * 2048 + qpos) * 4096 + h * 128;
#pragma unroll
            for (int dt = 0; dt < 8; ++dt)
                op[dt * 16 + m16] = (f16)(oacc[dt][r] * inv);
        }
        // next half's k-loop starts with BARRIER(), protecting LDS reuse
    }
}

// ---------------------------------------------------------------- launch
extern "C" void kernel_launch(void* const* d_in, const int* in_sizes, int n_in,
                              void* d_out, int out_size, void* d_ws, size_t ws_size,
                              hipStream_t stream) {
    const float* x     = (const float*)d_in[0];   // [2,2048,4096]
    const float* wqkv  = (const float*)d_in[1];   // [6144,4096]
    const float* wo    = (const float*)d_in[2];   // [4096,4096]
    const float* freqs = (const float*)d_in[3];   // [2048,1,64,2]
    const int*   seql  = (const int*)d_in[7];     // [2]
    float* out = (float*)d_out;

    char* ws = (char*)d_ws;
    size_t o = 0;
    f16* xh    = (f16*)(ws + o); o += (size_t)4096 * 4096 * 2;   // reused as attn_h
    f16* wqkvh = (f16*)(ws + o); o += (size_t)6144 * 4096 * 2;
    f16* woh   = (f16*)(ws + o); o += (size_t)4096 * 4096 * 2;
    f16* qkvh  = (f16*)(ws + o); o += (size_t)4096 * 6144 * 2;   // v section only
    f16* qhp   = (f16*)(ws + o); o += (size_t)4096 * 4096 * 2;
    f16* kkp   = (f16*)(ws + o); o += (size_t)4096 * 8 * 128 * 2;
    f16* vvt   = (f16*)(ws + o); o += (size_t)4096 * 8 * 128 * 2;
    f16* attnh = xh;  // xh dead after GEMM1

    cvt_f32_f16<<<16384, 256, 0, stream>>>(x, xh, 4194304);
    cvt_f32_f16<<<24576, 256, 0, stream>>>(wqkv, wqkvh, 6291456);
    cvt_f32_f16<<<16384, 256, 0, stream>>>(wo, woh, 4194304);

    // QKV GEMM with fused RoPE + paged-cache scatter (q->qhp scaled, k->kkp,
    // v->qkvh). rope_qk kernel eliminated.
    gemm256<f16, true><<<384, 512, 0, stream>>>(xh, wqkvh, qkvh, 4096, 6144, 4096,
                                                freqs, qhp, kkp);

    transpose_v<<<dim3(32, 2, 16), 256, 0, stream>>>(qkvh, vvt);

    attn_fused<<<dim3(8, 32, 2), 512, 0, stream>>>(qhp, kkp, vvt, seql, attnh);

    gemm256<float, false><<<256, 512, 0, stream>>>(attnh, woh, out, 4096, 4096, 4096,
                                                   nullptr, nullptr, nullptr);
}

// Round 12
// 798.809 us; speedup vs baseline: 1.0572x; 1.0572x over previous
//
#include <hip/hip_runtime.h>
#include <hip/hip_fp16.h>

typedef _Float16 f16;
typedef _Float16 f16x4 __attribute__((ext_vector_type(4)));
typedef _Float16 f16x8 __attribute__((ext_vector_type(8)));
typedef float    f32x4 __attribute__((ext_vector_type(4)));

#define NEG_INF (-__builtin_inff())
#define AS1 __attribute__((address_space(1)))
#define AS3 __attribute__((address_space(3)))
#define GLOAD_LDS16(g, l) \
    __builtin_amdgcn_global_load_lds((AS1 const void*)(g), (AS3 void*)(l), 16, 0, 0)
// v_exp_f32 computes 2^x; this builtin maps to it directly (NOT __exp2f, which
// collides with glibc math.h and does not exist as a HIP device function).
#define EXP2F(x) __builtin_amdgcn_exp2f(x)
// scale * log2(e): softmax runs in the log2 domain; folded into Q in rope_qk.
#define QSCL2 (0.08838834764831845f * 1.4426950408889634f)
// s_barrier is IntrNoMem at IR level: bracket with compile-time fences so no
// memory op (ds_read / global_load_lds) can be scheduled across a phase edge.
#define BARRIER() do { asm volatile("" ::: "memory"); \
                       __builtin_amdgcn_s_barrier(); \
                       asm volatile("" ::: "memory"); } while (0)

// ---------------------------------------------------------------- converts
__global__ __launch_bounds__(256) void cvt_f32_f16(const float* __restrict__ in,
                                                   f16* __restrict__ out, int n4) {
    int i = blockIdx.x * 256 + threadIdx.x;
    if (i >= n4) return;
    float4 v = ((const float4*)in)[i];
    f16x4 h = {(f16)v.x, (f16)v.y, (f16)v.z, (f16)v.w};
    ((f16x4*)out)[i] = h;
}

// ---------------------------------------------------------------- GEMM C = A * Bt^T
// FROZEN (r8/r10, 258-260 us, MfmaUtil ~34): r3 barrier/staging ledger +
// fragment prefetch under MFMA clusters. r4/r6/r8 scheduling attempts were
// null/negative; r11's epilogue-fused RoPE REGRESSED +52us (latency-bound
// scatter work at 1-block/CU occupancy loses the TLP that made it cheap as a
// standalone kernel). Keep the GEMM pure. Do not touch.
template <typename CT>
__global__ __launch_bounds__(512) void gemm256(const f16* __restrict__ A,
                                               const f16* __restrict__ Bt,
                                               CT* __restrict__ C,
                                               int M, int N, int K) {
    __shared__ __align__(16) f16 smem[65536];     // LA[2][2][8192] | LB[2][2][8192]
    f16* LA = smem;
    f16* LB = smem + 32768;

    const int tid  = threadIdx.x;
    const int wave = tid >> 6, lane = tid & 63;
    const int quad = lane >> 4, m16 = lane & 15;
    const int wm = wave >> 2, wn = wave & 3;

    // bijective XCD-aware block swizzle (m204 form)
    const int ntn = N >> 8;
    const int nwg = (M >> 8) * ntn;
    const int q8 = nwg >> 3, r8 = nwg & 7;
    const int xcd = blockIdx.x & 7, idx = blockIdx.x >> 3;
    const int swz = (xcd < r8 ? xcd * (q8 + 1) : r8 * (q8 + 1) + (xcd - r8) * q8) + idx;
    const int bm = (swz / ntn) << 8;
    const int bn = (swz % ntn) << 8;

    // staging: thread tid fills linear LDS elems tid*8 (+4096 for rows 64..127);
    // source column-granule XOR-pre-permuted so swizzled reads see logical data.
    const int rowW = tid >> 3;                         // 0..63
    const int gsrc = (tid & 7) ^ (rowW & 7);
    const f16* gA0 = A  + (size_t)(bm + rowW) * K + gsrc * 8;
    const f16* gA1 = A  + (size_t)(bm + 128 + rowW) * K + gsrc * 8;
    const f16* gB0 = Bt + (size_t)(bn + rowW) * K + gsrc * 8;
    const f16* gB1 = Bt + (size_t)(bn + 128 + rowW) * K + gsrc * 8;
    const size_t rstep = (size_t)64 * K;
    const int lw = wave * 512;                         // wave-uniform LDS elem offset

#define STG(dstbase, gp, kt) do { \
    GLOAD_LDS16((gp) + (size_t)(kt) * 64,         (dstbase) + lw); \
    GLOAD_LDS16((gp) + (size_t)(kt) * 64 + rstep, (dstbase) + lw + 4096); } while (0)

    // fragment LDS offsets (elems): row*64 + (((ks*4+quad) ^ (row&7))*8
    int foff[2];
#pragma unroll
    for (int ks = 0; ks < 2; ++ks)
        foff[ks] = (((ks << 2) | quad) ^ (m16 & 7)) * 8;
    const int arow = wm * 8192 + m16 * 64;             // + mt*1024
    const int brow = (wn >> 1) * 8192 + (wn & 1) * 4096 + m16 * 64;   // + nt*1024

    f32x4 acc[8][4];
#pragma unroll
    for (int i = 0; i < 8; ++i)
#pragma unroll
        for (int j = 0; j < 4; ++j)
#pragma unroll
            for (int e = 0; e < 4; ++e) acc[i][j][e] = 0.f;

    const int NT = K >> 6;

    // prologue: tile0 {A0,A1,B0,B1} + tile1 {B0,B1}; vmcnt(4) lands tile0;
    // then prefetch tile0's ph0 fragments (afA m0 + bf0) before entering loop.
    STG(LA, gA0, 0); STG(LA + 8192, gA1, 0);
    STG(LB, gB0, 0); STG(LB + 8192, gB1, 0);
    STG(LB + 16384, gB0, 1); STG(LB + 16384 + 8192, gB1, 1);
    asm volatile("s_waitcnt vmcnt(4)" ::: "memory");
    BARRIER();

    f16x8 afA[4][2], afB[4][2], bf0[2][2], bf1[2][2];
#pragma unroll
    for (int mt = 0; mt < 4; ++mt)
#pragma unroll
        for (int ks = 0; ks < 2; ++ks)
            afA[mt][ks] = *(const f16x8*)(LA + arow + mt * 1024 + foff[ks]);
#pragma unroll
    for (int nt = 0; nt < 2; ++nt)
#pragma unroll
        for (int ks = 0; ks < 2; ++ks)
            bf0[nt][ks] = *(const f16x8*)(LB + brow + nt * 1024 + foff[ks]);

    for (int t = 0; t < NT; ++t) {
        const int bo = (t & 1) * 16384;
        const f16* pa = LA + bo + arow;
        const f16* pb = LB + bo + brow;
        const f16* pa1 = LA + (bo ^ 16384) + arow;     // next tile's buffer
        const f16* pb1 = LB + (bo ^ 16384) + brow;

        // ---- phase 0: stage A-h0(t+1); MFMA(afA,bf0) ∥ prefetch bf1(t)
        if (t + 1 < NT) STG(LA + (bo ^ 16384), gA0, t + 1);
        BARRIER();
        asm volatile("s_waitcnt lgkmcnt(0)" ::: "memory");
        __builtin_amdgcn_s_setprio(1);
#pragma unroll
        for (int nt = 0; nt < 2; ++nt)
#pragma unroll
            for (int ks = 0; ks < 2; ++ks)
                bf1[nt][ks] = *(const f16x8*)(pb + (nt + 2) * 1024 + foff[ks]);
#pragma unroll
        for (int mt = 0; mt < 4; ++mt)
#pragma unroll
            for (int nt = 0; nt < 2; ++nt)
#pragma unroll
                for (int ks = 0; ks < 2; ++ks)
                    acc[mt][nt] = __builtin_amdgcn_mfma_f32_16x16x32_f16(
                        afA[mt][ks], bf0[nt][ks], acc[mt][nt], 0, 0, 0);
        __builtin_amdgcn_s_setprio(0);
        BARRIER();

        // ---- phase 1: stage A-h1(t+1); MFMA(afA,bf1) ∥ prefetch afB(t,m1)
        if (t + 1 < NT) STG(LA + (bo ^ 16384) + 8192, gA1, t + 1);
        BARRIER();
        asm volatile("s_waitcnt lgkmcnt(0)" ::: "memory");
        __builtin_amdgcn_s_setprio(1);
#pragma unroll
        for (int mt = 0; mt < 4; ++mt)
#pragma unroll
            for (int ks = 0; ks < 2; ++ks)
                afB[mt][ks] = *(const f16x8*)(pa + (mt + 4) * 1024 + foff[ks]);
#pragma unroll
        for (int mt = 0; mt < 4; ++mt)
#pragma unroll
            for (int nt = 0; nt < 2; ++nt)
#pragma unroll
                for (int ks = 0; ks < 2; ++ks)
                    acc[mt][nt + 2] = __builtin_amdgcn_mfma_f32_16x16x32_f16(
                        afA[mt][ks], bf1[nt][ks], acc[mt][nt + 2], 0, 0, 0);
        __builtin_amdgcn_s_setprio(0);
        BARRIER();

        // ---- phase 2: stage B-h0(t+2); MFMA(afB,bf1)
        if (t + 2 < NT) STG(LB + bo, gB0, t + 2);
        BARRIER();
        asm volatile("s_waitcnt lgkmcnt(0)" ::: "memory");
        __builtin_amdgcn_s_setprio(1);
#pragma unroll
        for (int mt = 0; mt < 4; ++mt)
#pragma unroll
            for (int nt = 0; nt < 2; ++nt)
#pragma unroll
                for (int ks = 0; ks < 2; ++ks)
                    acc[mt + 4][nt + 2] = __builtin_amdgcn_mfma_f32_16x16x32_f16(
                        afB[mt][ks], bf1[nt][ks], acc[mt + 4][nt + 2], 0, 0, 0);
        __builtin_amdgcn_s_setprio(0);
        BARRIER();

        // ---- phase 3: stage B-h1(t+2); vmcnt+BAR (A/B(t+1) visible);
        //      MFMA(afB,bf0) ∥ prefetch afA(t+1); THEN prefetch bf0(t+1)
        //      (bf0(t) must be consumed by the MFMA before being overwritten)
        if (t + 2 < NT) STG(LB + bo + 8192, gB1, t + 2);
        if (t + 2 < NT) { asm volatile("s_waitcnt vmcnt(4)" ::: "memory"); }
        else            { asm volatile("s_waitcnt vmcnt(0)" ::: "memory"); }
        BARRIER();
        __builtin_amdgcn_s_setprio(1);
        if (t + 1 < NT) {
#pragma unroll
            for (int mt = 0; mt < 4; ++mt)
#pragma unroll
                for (int ks = 0; ks < 2; ++ks)
                    afA[mt][ks] = *(const f16x8*)(pa1 + mt * 1024 + foff[ks]);
        }
#pragma unroll
        for (int mt = 0; mt < 4; ++mt)
#pragma unroll
            for (int nt = 0; nt < 2; ++nt)
#pragma unroll
                for (int ks = 0; ks < 2; ++ks)
                    acc[mt + 4][nt] = __builtin_amdgcn_mfma_f32_16x16x32_f16(
                        afB[mt][ks], bf0[nt][ks], acc[mt + 4][nt], 0, 0, 0);
        if (t + 1 < NT) {
#pragma unroll
            for (int nt = 0; nt < 2; ++nt)
#pragma unroll
                for (int ks = 0; ks < 2; ++ks)
                    bf0[nt][ks] = *(const f16x8*)(pb1 + nt * 1024 + foff[ks]);
        }
        __builtin_amdgcn_s_setprio(0);
        BARRIER();
    }
#undef STG

    // epilogue: row = bm + wm*128 + mt*16 + quad*4 + r, col = bn + wn*64 + nt*16 + m16
#pragma unroll
    for (int mt = 0; mt < 8; ++mt)
#pragma unroll
        for (int r = 0; r < 4; ++r) {
            int row = bm + wm * 128 + mt * 16 + quad * 4 + r;
            CT* cp = C + (size_t)row * N + bn + wn * 64 + m16;
#pragma unroll
            for (int nt = 0; nt < 4; ++nt) cp[nt * 16] = (CT)acc[mt][nt][r];
        }
}

// ---------------------------------------------------------------- RoPE (q,k only)
// Paged cache scatter+gather through an injective block_table is the identity on
// (b,s) -> skip the cache. qkv row: q 0:4096 | k 4096:5120 | v 5120:6144.
// r12: vectorized 4 pairs (8 f16) per thread -- f16x8 in, 2x float4 freqs,
// f16x8 out (16B/lane on all three streams). Q path pre-multiplied by
// scale*log2e (QSCL2) so attn consumes Q directly (exact: one multiply folded
// into a memory-bound kernel). Grid: B*S*40heads*16 groups / 256 = 10240.
__global__ __launch_bounds__(256) void rope_qk(const f16* __restrict__ qkv,
                                               const float* __restrict__ freqs,
                                               f16* __restrict__ qh,
                                               f16* __restrict__ kk) {
    int idx  = blockIdx.x * 256 + threadIdx.x;     // row-groups: 4096 rows x 640
    int row  = idx / 640;
    int g    = idx - row * 640;
    int b    = row >> 11, s = row & 2047;
    int head = g >> 4, i8 = (g & 15) * 8;          // f16 offset within head

    f16x8 x = *(const f16x8*)(qkv + (size_t)row * 6144 + head * 128 + i8);
    const float* fr = freqs + (size_t)s * 128 + i8;
    float4 f0 = *(const float4*)fr;                // cos0,sin0,cos1,sin1
    float4 f1 = *(const float4*)(fr + 4);          // cos2,sin2,cos3,sin3

    float c0 = f0.x, s0 = f0.y, c1 = f0.z, s1 = f0.w;
    float c2 = f1.x, s2 = f1.y, c3 = f1.z, s3 = f1.w;
    float o0 = (float)x[0] * c0 - (float)x[1] * s0;
    float o1 = (float)x[1] * c0 + (float)x[0] * s0;
    float o2 = (float)x[2] * c1 - (float)x[3] * s1;
    float o3 = (float)x[3] * c1 + (float)x[2] * s1;
    float o4 = (float)x[4] * c2 - (float)x[5] * s2;
    float o5 = (float)x[5] * c2 + (float)x[4] * s2;
    float o6 = (float)x[6] * c3 - (float)x[7] * s3;
    float o7 = (float)x[7] * c3 + (float)x[6] * s3;

    f16* dst;
    if (head < 32) {
        o0 *= QSCL2; o1 *= QSCL2; o2 *= QSCL2; o3 *= QSCL2;
        o4 *= QSCL2; o5 *= QSCL2; o6 *= QSCL2; o7 *= QSCL2;
        dst = qh + (((size_t)(b * 32 + head)) * 2048 + s) * 128 + i8;
    } else {
        dst = kk + (((size_t)(b * 8 + head - 32)) * 2048 + s) * 128 + i8;
    }
    f16x8 o = {(f16)o0, (f16)o1, (f16)o2, (f16)o3, (f16)o4, (f16)o5, (f16)o6, (f16)o7};
    *(f16x8*)dst = o;
}

// ---------------------------------------------------------------- V transpose (LDS-tiled)
__global__ __launch_bounds__(256) void transpose_v(const f16* __restrict__ qkv,
                                                   f16* __restrict__ vvt) {
    __shared__ f16 T[64][72];
    const int st = blockIdx.x, dt = blockIdx.y;
    const int b = blockIdx.z >> 3, kvh = blockIdx.z & 7;
    const int tid = threadIdx.x;
    const int sr = tid >> 3, c8 = (tid & 7) * 8;
#pragma unroll
    for (int rep = 0; rep < 2; ++rep) {
        int sl = rep * 32 + sr;
        *(f16x8*)&T[sl][c8] =
            *(const f16x8*)(qkv + (size_t)(b * 2048 + st * 64 + sl) * 6144
                            + 5120 + kvh * 128 + dt * 64 + c8);
    }
    __syncthreads();
#pragma unroll
    for (int rep = 0; rep < 2; ++rep) {
        int dl = rep * 32 + sr;
        f16x8 v;
#pragma unroll
        for (int j = 0; j < 8; ++j) v[j] = T[c8 + j][dl];
        *(f16x8*)(vvt + (((size_t)(b * 8 + kvh)) * 128 + dt * 64 + dl) * 2048
                  + st * 64 + c8) = v;
    }
}

// ---------------------------------------------------------------- flash attention v7b
// v7 structure (512 thr / 8 waves, QBLK=128, 2 barriers/ktile, T14 async
// staging, mask-skip, defer-rescale, partial l_i). Q arrives PRE-SCALED by
// scale*log2e from rope_qk (no per-half scaling loop here).
__global__ __launch_bounds__(512) void attn_fused(const f16* __restrict__ qh,
                                                  const f16* __restrict__ kk,
                                                  const f16* __restrict__ vvt,
                                                  const int* __restrict__ seqlens,
                                                  f16* __restrict__ out) {
    __shared__ f16 Ks[64 * 136];     // [key][d] stride 136
    __shared__ f16 Vs[128][72];      // [d][key] stride 72 (2-way free)
    __shared__ f16 Ps[128 * 72];     // [qrow][key] stride 72, wave-private rows
    const int pair = blockIdx.x;     // 0..7
    const int h = blockIdx.y, b = blockIdx.z;
    const int kvh = h >> 2;
    const int tid = threadIdx.x, wave = tid >> 6, lane = tid & 63;
    const int quad = lane >> 4, m16 = lane & 15;

    const int seqlen = seqlens[b];
    const f16* kbp = kk  + ((size_t)(b * 8 + kvh) * 2048) * 128;
    const f16* vbp = vvt + ((size_t)(b * 8 + kvh) * 128) * 2048;

    for (int half = 0; half < 2; ++half) {
        const int qt = half ? pair : (15 - pair);   // heavy tile first
        const int qbase = qt * 128;
        const int qw = qbase + wave * 16;

        const f16* qptr = qh + (((size_t)(b * 32 + h)) * 2048 + qw + m16) * 128;
        f16x8 qf[4];
#pragma unroll
        for (int c = 0; c < 4; ++c) qf[c] = *(const f16x8*)(qptr + c * 32 + quad * 8);

        float m_i[4], l_i[4];
        f32x4 oacc[8];
#pragma unroll
        for (int r = 0; r < 4; ++r) { m_i[r] = NEG_INF; l_i[r] = 0.f; }
#pragma unroll
        for (int dt = 0; dt < 8; ++dt)
#pragma unroll
            for (int e = 0; e < 4; ++e) oacc[dt][e] = 0.f;

        int kmax = qbase + 128; if (seqlen < kmax) kmax = seqlen;

        // prefetch tile 0 into registers (512 threads: 2 chunks each of K and V)
        f16x8 gk[2], gv[2];
#pragma unroll
        for (int it = 0; it < 2; ++it) {
            int g = it * 512 + tid;
            gk[it] = *(const f16x8*)(kbp + (size_t)(g >> 4) * 128 + (g & 15) * 8);
            gv[it] = *(const f16x8*)(vbp + (size_t)(g >> 3) * 2048 + (g & 7) * 8);
        }

        for (int kt = 0; kt < kmax; kt += 64) {
            BARRIER();   // all waves' Ks/Vs reads of prev iter are complete
            // reg -> LDS (K tile: 64 keys x 128 d; V^T tile: 128 d x 64 keys)
#pragma unroll
            for (int it = 0; it < 2; ++it) {
                int g = it * 512 + tid;
                *(f16x8*)&Ks[(g >> 4) * 136 + (g & 15) * 8] = gk[it];
                *(f16x8*)&Vs[g >> 3][(g & 7) * 8] = gv[it];
            }
            // issue next tile's loads; they stay in flight across the barrier
            if (kt + 64 < kmax) {
#pragma unroll
                for (int it = 0; it < 2; ++it) {
                    int g = it * 512 + tid;
                    gk[it] = *(const f16x8*)(kbp + (size_t)(kt + 64 + (g >> 4)) * 128 + (g & 15) * 8);
                    gv[it] = *(const f16x8*)(vbp + (size_t)(g >> 3) * 2048 + (kt + 64) + (g & 7) * 8);
                }
            }
            asm volatile("s_waitcnt lgkmcnt(0)" ::: "memory");  // LDS writes visible
            BARRIER();                                          // vmcnt NOT drained

            // S = Q K^T (Q pre-scaled, log2 domain)
            f32x4 sc[4];
#pragma unroll
            for (int nt = 0; nt < 4; ++nt) {
                f32x4 s = {0.f, 0.f, 0.f, 0.f};
#pragma unroll
                for (int c = 0; c < 4; ++c) {
                    f16x8 kf = *(const f16x8*)&Ks[(nt * 16 + m16) * 136 + c * 32 + quad * 8];
                    s = __builtin_amdgcn_mfma_f32_16x16x32_f16(qf[c], kf, s, 0, 0, 0);
                }
                sc[nt] = s;
            }

            // mask only on diagonal/partial tiles (wave-uniform branch)
            float sv[4][4];
            float mt[4] = {NEG_INF, NEG_INF, NEG_INF, NEG_INF};
            if (kt + 63 <= qw && kt + 64 <= seqlen) {
#pragma unroll
                for (int nt = 0; nt < 4; ++nt)
#pragma unroll
                    for (int r = 0; r < 4; ++r) {
                        float sx = sc[nt][r];
                        sv[nt][r] = sx;
                        mt[r] = fmaxf(mt[r], sx);
                    }
            } else {
#pragma unroll
                for (int nt = 0; nt < 4; ++nt) {
                    int kpos = kt + nt * 16 + m16;
#pragma unroll
                    for (int r = 0; r < 4; ++r) {
                        int qpos = qw + quad * 4 + r;
                        float sx = sc[nt][r];
                        sx = (kpos <= qpos && kpos < seqlen) ? sx : NEG_INF;
                        sv[nt][r] = sx;
                        mt[r] = fmaxf(mt[r], sx);
                    }
                }
            }
#pragma unroll
            for (int off = 1; off < 16; off <<= 1)
#pragma unroll
                for (int r = 0; r < 4; ++r)
                    mt[r] = fmaxf(mt[r], __shfl_xor(mt[r], off, 64));

            // exact defer: skip alpha+rescale entirely when no row's max grew
            // (alpha==1). mt/m_i uniform across m16; branch diverges only
            // across quad groups (both paths per-lane correct).
            float mm[4];
            bool grow = (mt[0] > m_i[0]) | (mt[1] > m_i[1]) |
                        (mt[2] > m_i[2]) | (mt[3] > m_i[3]);
            if (grow) {
#pragma unroll
                for (int r = 0; r < 4; ++r) {
                    float mo = m_i[r];
                    float mn = fmaxf(mo, mt[r]);
                    float mmr = fmaxf(mn, -1e30f);
                    float a = EXP2F(mo - mmr);
                    m_i[r] = mn;
                    mm[r] = mmr;
                    l_i[r] *= a;     // per-lane PARTIAL; a uniform across m16
#pragma unroll
                    for (int dt = 0; dt < 8; ++dt) oacc[dt][r] *= a;
                }
            } else {
#pragma unroll
                for (int r = 0; r < 4; ++r) mm[r] = fmaxf(m_i[r], -1e30f);
            }
            // per-lane partial row-sum: no cross-lane reduce here (epilogue)
#pragma unroll
            for (int nt = 0; nt < 4; ++nt)
#pragma unroll
                for (int r = 0; r < 4; ++r) {
                    float pv = EXP2F(sv[nt][r] - mm[r]);
                    sv[nt][r] = pv;
                    l_i[r] += pv;
                }

            // P: C-layout regs -> WAVE-PRIVATE Ps rows -> A-layout fragments.
            // No barrier: rows [wave*16, wave*16+16) are touched only by this
            // wave; compiler orders the ds_write -> ds_read via lgkmcnt.
#pragma unroll
            for (int nt = 0; nt < 4; ++nt)
#pragma unroll
                for (int r = 0; r < 4; ++r)
                    Ps[(wave * 16 + quad * 4 + r) * 72 + nt * 16 + m16] = (f16)sv[nt][r];

            f16x8 pf[2];
#pragma unroll
            for (int c = 0; c < 2; ++c)
                pf[c] = *(const f16x8*)&Ps[(wave * 16 + m16) * 72 + c * 32 + quad * 8];
#pragma unroll
            for (int dt = 0; dt < 8; ++dt)
#pragma unroll
                for (int c = 0; c < 2; ++c) {
                    f16x8 vf = *(const f16x8*)&Vs[dt * 16 + m16][c * 32 + quad * 8];
                    oacc[dt] = __builtin_amdgcn_mfma_f32_16x16x32_f16(pf[c], vf, oacc[dt], 0, 0, 0);
                }
        }

        // epilogue: ONE cross-lane reduce of the partial l_i, then normalize
#pragma unroll
        for (int off = 1; off < 16; off <<= 1)
#pragma unroll
            for (int r = 0; r < 4; ++r) l_i[r] += __shfl_xor(l_i[r], off, 64);
#pragma unroll
        for (int r = 0; r < 4; ++r) {
            int qpos = qw + quad * 4 + r;
            float inv = 1.0f / l_i[r];
            f16* op = out + ((size_t)b * 2048 + qpos) * 4096 + h * 128;
#pragma unroll
            for (int dt = 0; dt < 8; ++dt)
                op[dt * 16 + m16] = (f16)(oacc[dt][r] * inv);
        }
        // next half's k-loop starts with BARRIER(), protecting LDS reuse
    }
}

// ---------------------------------------------------------------- launch
extern "C" void kernel_launch(void* const* d_in, const int* in_sizes, int n_in,
                              void* d_out, int out_size, void* d_ws, size_t ws_size,
                              hipStream_t stream) {
    const float* x     = (const float*)d_in[0];   // [2,2048,4096]
    const float* wqkv  = (const float*)d_in[1];   // [6144,4096]
    const float* wo    = (const float*)d_in[2];   // [4096,4096]
    const float* freqs = (const float*)d_in[3];   // [2048,1,64,2]
    const int*   seql  = (const int*)d_in[7];     // [2]
    float* out = (float*)d_out;

    char* ws = (char*)d_ws;
    size_t o = 0;
    f16* xh    = (f16*)(ws + o); o += (size_t)4096 * 4096 * 2;   // reused as attn_h
    f16* wqkvh = (f16*)(ws + o); o += (size_t)6144 * 4096 * 2;
    f16* woh   = (f16*)(ws + o); o += (size_t)4096 * 4096 * 2;
    f16* qkvh  = (f16*)(ws + o); o += (size_t)4096 * 6144 * 2;
    f16* qhp   = (f16*)(ws + o); o += (size_t)4096 * 4096 * 2;
    f16* kkp   = (f16*)(ws + o); o += (size_t)4096 * 8 * 128 * 2;
    f16* vvt   = (f16*)(ws + o); o += (size_t)4096 * 8 * 128 * 2;
    f16* attnh = xh;  // xh dead after GEMM1

    cvt_f32_f16<<<16384, 256, 0, stream>>>(x, xh, 4194304);
    cvt_f32_f16<<<24576, 256, 0, stream>>>(wqkv, wqkvh, 6291456);
    cvt_f32_f16<<<16384, 256, 0, stream>>>(wo, woh, 4194304);

    gemm256<f16><<<384, 512, 0, stream>>>(xh, wqkvh, qkvh, 4096, 6144, 4096);

    rope_qk<<<10240, 256, 0, stream>>>(qkvh, freqs, qhp, kkp);
    transpose_v<<<dim3(32, 2, 16), 256, 0, stream>>>(qkvh, vvt);

    attn_fused<<<dim3(8, 32, 2), 512, 0, stream>>>(qhp, kkp, vvt, seql, attnh);

    gemm256<float><<<256, 512, 0, stream>>>(attnh, woh, out, 4096, 4096, 4096);
}